// Round 9
// baseline (64.216 us; speedup 1.0000x reference)
//
#include <hip/hip_runtime.h>
#include <stdint.h>

typedef _Float16 f16x8 __attribute__((ext_vector_type(8)));
typedef float    f32x4 __attribute__((ext_vector_type(4)));

union FragU { unsigned u[4]; f16x8 h; };

__device__ __forceinline__ unsigned pkh(float a, float b) {
    return __builtin_bit_cast(unsigned, __builtin_amdgcn_cvt_pkrtz(a, b));
}
__device__ __forceinline__ unsigned short h16(float a) {
    return __builtin_bit_cast(unsigned short, (_Float16)a);
}

#define MFMA(A, B, C) __builtin_amdgcn_mfma_f32_16x16x32_f16((A).h, (B).h, (C), 0, 0, 0)

#define K1 (-1.5339807878856412e-03f)   /* -2*pi/4096 */
#define K2 (-2.4543692606170259e-02f)   /* -2*pi/256  */

// 4096-pt FFT = 3 radix-16 stages as complex 16x16 GEMMs (K=32 stacking).
// TWO rows per block (bh and bh+BH/2, same h -> shared M frags + twiddles),
// software-pipelined: row B's global loads issue right after row A's first
// barrier and complete under A's stage2/3/store. Barrier between stage2 and
// stage3 removed (LDS2 traffic is wave-local under the XOR swizzle).
// LDS 32 KiB: LDS1 [m1][o3][o2] @0/@8192, LDS2 [m2][m1][o3] @16384/@24576,
// F [n3][(m2,m1)^swz] float2 overlays everything.
__global__ __launch_bounds__(256, 4) void fft4096_mfma(
    const float* __restrict__ xre, const float* __restrict__ xim,
    const float* __restrict__ mat16, float* __restrict__ out, int H, int BH)
{
    __shared__ __align__(16) unsigned char smem[32768];

    const int t = threadIdx.x;
    const int w = t >> 6;          // wave 0..3
    const int l = t & 63;
    const int g = l >> 4;          // lane group 0..3
    const int c = l & 15;          // lane col 0..15

    const int rowA = blockIdx.x;               // 0..BH/2-1
    const int rowB = rowA + (BH >> 1);         // same h ((BH/2)%H==0)
    const int h    = rowA % H;
    const size_t baseA = (size_t)rowA * 4096;
    const size_t baseB = (size_t)rowB * 4096;

    // ---- row A input loads issued first (deep MLP) ----
    float xAr[4][4], xAi[4][4], xBr[4][4], xBi[4][4];
#pragma unroll
    for (int p = 0; p < 4; ++p) {
        const int col = (4 * w + p) * 16 + c;
#pragma unroll
        for (int jj = 0; jj < 4; ++jj) {
            xAr[p][jj] = xre[baseA + (size_t)((4 * g + jj) * 256 + col)];
            xAi[p][jj] = xim[baseA + (size_t)((4 * g + jj) * 256 + col)];
        }
    }

    // ---- M fragments (one load, reused by all stages of BOTH rows) ----
    const float* Mb = mat16 + (size_t)h * 512 + (size_t)c * 32 + g * 8;
    const float4 mf0 = *(const float4*)Mb;
    const float4 mf1 = *(const float4*)(Mb + 4);
    const unsigned mrA = pkh(mf0.x, mf0.z), mrB = pkh(mf1.x, mf1.z);
    const unsigned miA = pkh(mf0.y, mf0.w), miB = pkh(mf1.y, mf1.w);
    const unsigned nmiA = miA ^ 0x80008000u, nmiB = miB ^ 0x80008000u;

    FragU Afrag;  // A = [Mr | Mi] (stages 1,2)
    Afrag.u[0] = mrA; Afrag.u[1] = mrB; Afrag.u[2] = miA; Afrag.u[3] = miB;
    FragU BMr;    // stage3 B for Vr^T: [Mr^T ; -Mi^T]
    BMr.u[0] = mrA; BMr.u[1] = mrB; BMr.u[2] = nmiA; BMr.u[3] = nmiB;
    FragU BMi;    // stage3 B for Vi^T: [Mi^T ; Mr^T]
    BMi.u[0] = miA; BMi.u[1] = miB; BMi.u[2] = mrA; BMi.u[3] = mrB;

    // stage-2 twiddle tw256(o3*m2): o3=c, m2=4g+reg (row-independent)
    float twc[4], tws[4];
    {
        float sb, cb, ss, cs;
        __sincosf(K2 * (float)(c * 4 * g), &sb, &cb);
        __sincosf(K2 * (float)c, &ss, &cs);
#pragma unroll
        for (int reg = 0; reg < 4; ++reg) {
            twc[reg] = cb; tws[reg] = sb;
            const float nc = cb * cs - sb * ss;
            const float ns = cb * ss + sb * cs;
            cb = nc; sb = ns;
        }
    }

    const f32x4 zero = {0.f, 0.f, 0.f, 0.f};
    f32x4* __restrict__ og4 = (f32x4*)out;

    // =================== two pipelined row iterations ======================
#pragma unroll
    for (int r = 0; r < 2; ++r) {
        const size_t base = r ? baseB : baseA;
        // static-indexed selection of this row's preloaded data (rule #20)
        // row 0 consumes xA*, row 1 consumes xB*.

        // ---------- stage 1: Y1[m1][j] = sum_o M[m1][o] x[o*256+j] ----------
        f32x4 s1r[4], s1i[4];
#pragma unroll
        for (int p = 0; p < 4; ++p) {
            float r0, r1, r2, r3, i0, i1, i2, i3;
            if (r == 0) {
                r0 = xAr[p][0]; r1 = xAr[p][1]; r2 = xAr[p][2]; r3 = xAr[p][3];
                i0 = xAi[p][0]; i1 = xAi[p][1]; i2 = xAi[p][2]; i3 = xAi[p][3];
            } else {
                r0 = xBr[p][0]; r1 = xBr[p][1]; r2 = xBr[p][2]; r3 = xBr[p][3];
                i0 = xBi[p][0]; i1 = xBi[p][1]; i2 = xBi[p][2]; i3 = xBi[p][3];
            }
            const unsigned rp0 = pkh(r0, r1), rp1 = pkh(r2, r3);
            const unsigned ip0 = pkh(i0, i1), ip1 = pkh(i2, i3);
            const unsigned np0 = ip0 ^ 0x80008000u, np1 = ip1 ^ 0x80008000u;
            FragU Br; Br.u[0] = rp0; Br.u[1] = rp1; Br.u[2] = np0; Br.u[3] = np1;
            FragU Bi; Bi.u[0] = ip0; Bi.u[1] = ip1; Bi.u[2] = rp0; Bi.u[3] = rp1;
            s1r[p] = MFMA(Afrag, Br, zero);
            s1i[p] = MFMA(Afrag, Bi, zero);
        }
        // twiddle tw4096(j*m1), m1 = 4g+reg
#pragma unroll
        for (int p = 0; p < 4; ++p) {
            const int j = (4 * w + p) * 16 + c;
            float sb, cb, ss, cs;
            __sincosf(K1 * (float)(j * 4 * g), &sb, &cb);
            __sincosf(K1 * (float)j, &ss, &cs);
#pragma unroll
            for (int reg = 0; reg < 4; ++reg) {
                const float yr = s1r[p][reg], yi = s1i[p][reg];
                s1r[p][reg] = yr * cb - yi * sb;
                s1i[p][reg] = yr * sb + yi * cb;
                const float nc = cb * cs - sb * ss;
                const float ns = cb * ss + sb * cs;
                cb = nc; sb = ns;
            }
        }
        // LDS1 [m1][o3][o2], o2-block XOR-swizzled
#pragma unroll
        for (int reg = 0; reg < 4; ++reg) {
            const int m1 = 4 * g + reg;
            const int half = m1 * 256 + c * 16 + 4 * ((w ^ (c >> 2) ^ reg) & 3);
            uint2 vr, vi;
            vr.x = pkh(s1r[0][reg], s1r[1][reg]); vr.y = pkh(s1r[2][reg], s1r[3][reg]);
            vi.x = pkh(s1i[0][reg], s1i[1][reg]); vi.y = pkh(s1i[2][reg], s1i[3][reg]);
            *(uint2*)(smem + half * 2)        = vr;
            *(uint2*)(smem + 8192 + half * 2) = vi;
        }
        __syncthreads();   // bar1: LDS1 ready (cross-wave)

        // ---------- prefetch row B's inputs under row A's compute ----------
        if (r == 0) {
#pragma unroll
            for (int p = 0; p < 4; ++p) {
                const int col = (4 * w + p) * 16 + c;
#pragma unroll
                for (int jj = 0; jj < 4; ++jj) {
                    xBr[p][jj] = xre[baseB + (size_t)((4 * g + jj) * 256 + col)];
                    xBi[p][jj] = xim[baseB + (size_t)((4 * g + jj) * 256 + col)];
                }
            }
        }

        // ---------- stage 2: A2[m2][o3] = sum_o2 M[m2][o2] T[o2*16+o3] ------
        f32x4 s2r[4], s2i[4];
#pragma unroll
        for (int p = 0; p < 4; ++p) {
            const int m1 = 4 * w + p;
            const int half = m1 * 256 + c * 16 + 4 * ((g ^ (c >> 2) ^ p) & 3);
            const uint2 rp = *(const uint2*)(smem + half * 2);
            const uint2 ip = *(const uint2*)(smem + 8192 + half * 2);
            FragU Br; Br.u[0] = rp.x; Br.u[1] = rp.y;
            Br.u[2] = ip.x ^ 0x80008000u; Br.u[3] = ip.y ^ 0x80008000u;
            FragU Bi; Bi.u[0] = ip.x; Bi.u[1] = ip.y; Bi.u[2] = rp.x; Bi.u[3] = rp.y;
            s2r[p] = MFMA(Afrag, Br, zero);
            s2i[p] = MFMA(Afrag, Bi, zero);
        }
#pragma unroll
        for (int p = 0; p < 4; ++p) {
#pragma unroll
            for (int reg = 0; reg < 4; ++reg) {
                const float yr = s2r[p][reg], yi = s2i[p][reg];
                s2r[p][reg] = yr * twc[reg] - yi * tws[reg];
                s2i[p][reg] = yr * tws[reg] + yi * twc[reg];
            }
        }
        // LDS2 [m2][m1][o3] XOR-swizzled; wave-local (m1 nibble stays in
        // {4w..4w+3} under the XOR) -> NO barrier before stage-3 reads.
#pragma unroll
        for (int reg = 0; reg < 4; ++reg) {
            const int m2 = 4 * g + reg;
#pragma unroll
            for (int p = 0; p < 4; ++p) {
                const int spos = (((4 * w + p) * 16 + c) ^ (g << 4)) ^ (reg << 2);
                const int half = m2 * 256 + spos;
                *(unsigned short*)(smem + 16384 + half * 2) = h16(s2r[p][reg]);
                *(unsigned short*)(smem + 24576 + half * 2) = h16(s2i[p][reg]);
            }
        }

        // ---------- stage 3: V^T[m2][n3] = sum_o3 U^T[m2][o3] M^T[o3][n3] ---
        FragU Aup[4];
#pragma unroll
        for (int p = 0; p < 4; ++p) {
            const int spos = ((((4 * w + p) * 16 + 4 * g) ^ (((c >> 2) & 3) << 4))
                              ^ ((c & 3) << 2));
            const int half = c * 256 + spos;
            const uint2 hr = *(const uint2*)(smem + 16384 + half * 2);
            const uint2 hi = *(const uint2*)(smem + 24576 + half * 2);
            Aup[p].u[0] = hr.x; Aup[p].u[1] = hr.y;
            Aup[p].u[2] = hi.x; Aup[p].u[3] = hi.y;
        }
        __syncthreads();   // bar3: all LDS2 writes+reads done before F overlay

        f32x4 vR[4], vI[4];
#pragma unroll
        for (int p = 0; p < 4; ++p) {
            vR[p] = MFMA(Aup[p], BMr, zero);
            vI[p] = MFMA(Aup[p], BMi, zero);
        }

        // F[n3][inner] float2, inner = (m2*16+m1) ^ ((n3&7)<<1); n3 = c
        {
            const int swz = (c & 7) << 1;
#pragma unroll
            for (int reg = 0; reg < 4; ++reg) {
                const int i0 = (((4 * g + reg) * 16 + 4 * w) ^ swz);
                const int i1 = (((4 * g + reg) * 16 + 4 * w + 2) ^ swz);
                const f32x4 a = {vR[0][reg], vI[0][reg], vR[1][reg], vI[1][reg]};
                const f32x4 b = {vR[2][reg], vI[2][reg], vR[3][reg], vI[3][reg]};
                *(f32x4*)(smem + (size_t)(c * 256 + i0) * 8) = a;
                *(f32x4*)(smem + (size_t)(c * 256 + i1) * 8) = b;
            }
        }
        __syncthreads();   // bar4: F ready

        // coalesced nontemporal stores: 16B (2 complex) per lane per iter
#pragma unroll
        for (int it = 0; it < 8; ++it) {
            const int jr = 2 * it + (t >> 7);
            const int u  = (t & 127) * 2;
            const int is = u ^ ((jr & 7) << 1);
            const f32x4 v = *(const f32x4*)(smem + (size_t)(jr * 256 + is) * 8);
            __builtin_nontemporal_store(v, &og4[(base + (size_t)(jr * 256 + u)) >> 1]);
        }
        if (r == 0) __syncthreads();   // bar5: F reads done before B's LDS1 writes
    }
}

extern "C" void kernel_launch(void* const* d_in, const int* in_sizes, int n_in,
                              void* d_out, int out_size, void* d_ws, size_t ws_size,
                              hipStream_t stream)
{
    const float* xre = (const float*)d_in[0];
    const float* xim = (const float*)d_in[1];
    const float* m16 = (const float*)d_in[5];   // (H,16,16,2) fp32
    const int H  = in_sizes[5] / 512;
    const int BH = in_sizes[0] / 4096;
    fft4096_mfma<<<dim3(BH / 2), dim3(256), 0, stream>>>(
        xre, xim, m16, (float*)d_out, H, BH);
}

// Round 10
// 45.923 us; speedup vs baseline: 1.3983x; 1.3983x over previous
//
#include <hip/hip_runtime.h>
#include <stdint.h>

typedef _Float16 f16x8 __attribute__((ext_vector_type(8)));
typedef float    f32x4 __attribute__((ext_vector_type(4)));

union FragU { unsigned u[4]; f16x8 h; };
union H2U  { unsigned u; _Float16 h[2]; };

__device__ __forceinline__ unsigned pkh(float a, float b) {
    return __builtin_bit_cast(unsigned, __builtin_amdgcn_cvt_pkrtz(a, b));
}
__device__ __forceinline__ unsigned short h16(float a) {
    return __builtin_bit_cast(unsigned short, (_Float16)a);
}

#define MFMA(A, B, C) __builtin_amdgcn_mfma_f32_16x16x32_f16((A).h, (B).h, (C), 0, 0, 0)

#define K1 (-1.5339807878856412e-03f)   /* -2*pi/4096 */
#define K2 (-2.4543692606170259e-02f)   /* -2*pi/256  */

// 4096-pt FFT = 3 radix-16 stages as complex 16x16 GEMMs (K=32 stacking).
// One block per (b,h) row, 4 waves. Round-8 dataflow, LDS halved to 16 KiB:
//   LDS1 [m1][o3][o2] fp16 halves @0/@8192       (stage1 -> stage2)
//   LDS2 [m2][m1][o3] fp16 halves, IN PLACE @0/@8192 (stage2 -> stage3;
//        stage-2 reads are pulled into registers first, one barrier, then
//        the region is overwritten)
//   F    [n3][pair^swz] half2, overlays @0..16K   (output transpose, fp16)
// 16 KiB -> up to 8 blocks/CU (wave-slot cap) vs ~3 before: more
// phase-independent blocks to keep the HBM read/write streams busy.
__global__ __launch_bounds__(256, 6) void fft4096_mfma(
    const float* __restrict__ xre, const float* __restrict__ xim,
    const float* __restrict__ mat16, float* __restrict__ out, int H)
{
    __shared__ __align__(16) unsigned char smem[16384];

    const int t = threadIdx.x;
    const int w = t >> 6;          // wave 0..3
    const int l = t & 63;
    const int g = l >> 4;          // lane group 0..3
    const int c = l & 15;          // lane col 0..15
    const int bh = blockIdx.x;
    const int h  = bh % H;
    const size_t base = (size_t)bh * 4096;

    // ---- all 64 stage-1 input loads issued first (deep MLP) ----
    float xr[4][4], xi[4][4];
#pragma unroll
    for (int p = 0; p < 4; ++p) {
        const int col = (4 * w + p) * 16 + c;
#pragma unroll
        for (int jj = 0; jj < 4; ++jj) {
            xr[p][jj] = xre[base + (size_t)((4 * g + jj) * 256 + col)];
            xi[p][jj] = xim[base + (size_t)((4 * g + jj) * 256 + col)];
        }
    }

    // ---- M fragments (one load, reused by all 3 stages) ----
    const float* Mb = mat16 + (size_t)h * 512 + (size_t)c * 32 + g * 8;
    const float4 mf0 = *(const float4*)Mb;
    const float4 mf1 = *(const float4*)(Mb + 4);
    const unsigned mrA = pkh(mf0.x, mf0.z), mrB = pkh(mf1.x, mf1.z);
    const unsigned miA = pkh(mf0.y, mf0.w), miB = pkh(mf1.y, mf1.w);
    const unsigned nmiA = miA ^ 0x80008000u, nmiB = miB ^ 0x80008000u;

    FragU Afrag;  // A = [Mr | Mi] (stages 1,2)
    Afrag.u[0] = mrA; Afrag.u[1] = mrB; Afrag.u[2] = miA; Afrag.u[3] = miB;
    FragU BMr;    // stage3 B for Vr^T: [Mr^T ; -Mi^T]
    BMr.u[0] = mrA; BMr.u[1] = mrB; BMr.u[2] = nmiA; BMr.u[3] = nmiB;
    FragU BMi;    // stage3 B for Vi^T: [Mi^T ; Mr^T]
    BMi.u[0] = miA; BMi.u[1] = miB; BMi.u[2] = mrA; BMi.u[3] = mrB;

    const f32x4 zero = {0.f, 0.f, 0.f, 0.f};

    // ================= stage 1: Y1[m1][j] = sum_o M[m1][o] x[o*256+j] =========
    f32x4 s1r[4], s1i[4];
#pragma unroll
    for (int p = 0; p < 4; ++p) {
        const unsigned rp0 = pkh(xr[p][0], xr[p][1]), rp1 = pkh(xr[p][2], xr[p][3]);
        const unsigned ip0 = pkh(xi[p][0], xi[p][1]), ip1 = pkh(xi[p][2], xi[p][3]);
        const unsigned np0 = ip0 ^ 0x80008000u, np1 = ip1 ^ 0x80008000u;
        FragU Br; Br.u[0] = rp0; Br.u[1] = rp1; Br.u[2] = np0; Br.u[3] = np1;
        FragU Bi; Bi.u[0] = ip0; Bi.u[1] = ip1; Bi.u[2] = rp0; Bi.u[3] = rp1;
        s1r[p] = MFMA(Afrag, Br, zero);
        s1i[p] = MFMA(Afrag, Bi, zero);
    }
    // twiddle tw4096(j*m1), m1 = 4g+reg
#pragma unroll
    for (int p = 0; p < 4; ++p) {
        const int j = (4 * w + p) * 16 + c;
        float sb, cb, ss, cs;
        __sincosf(K1 * (float)(j * 4 * g), &sb, &cb);
        __sincosf(K1 * (float)j, &ss, &cs);
#pragma unroll
        for (int reg = 0; reg < 4; ++reg) {
            const float yr = s1r[p][reg], yi = s1i[p][reg];
            s1r[p][reg] = yr * cb - yi * sb;
            s1i[p][reg] = yr * sb + yi * cb;
            const float nc = cb * cs - sb * ss;
            const float ns = cb * ss + sb * cs;
            cb = nc; sb = ns;
        }
    }
    // LDS1 [m1][o3][o2], o2-block XOR-swizzled: s = (w ^ (c>>2) ^ reg) & 3
#pragma unroll
    for (int reg = 0; reg < 4; ++reg) {
        const int m1 = 4 * g + reg;
        const int half = m1 * 256 + c * 16 + 4 * ((w ^ (c >> 2) ^ reg) & 3);
        uint2 vr, vi;
        vr.x = pkh(s1r[0][reg], s1r[1][reg]); vr.y = pkh(s1r[2][reg], s1r[3][reg]);
        vi.x = pkh(s1i[0][reg], s1i[1][reg]); vi.y = pkh(s1i[2][reg], s1i[3][reg]);
        *(uint2*)(smem + half * 2)        = vr;
        *(uint2*)(smem + 8192 + half * 2) = vi;
    }
    __syncthreads();   // bar1: LDS1 ready

    // ================= stage 2: A2[m2][o3] = sum_o2 M[m2][o2] T[o2*16+o3] =====
    // Read ALL wave-local tiles into registers, MFMA them, THEN barrier and
    // overwrite the region with LDS2 (in-place overlay).
    uint2 rp[4], ip[4];
#pragma unroll
    for (int p = 0; p < 4; ++p) {
        const int m1 = 4 * w + p;
        const int half = m1 * 256 + c * 16 + 4 * ((g ^ (c >> 2) ^ p) & 3);
        rp[p] = *(const uint2*)(smem + half * 2);
        ip[p] = *(const uint2*)(smem + 8192 + half * 2);
    }
    f32x4 s2r[4], s2i[4];
#pragma unroll
    for (int p = 0; p < 4; ++p) {
        FragU Br; Br.u[0] = rp[p].x; Br.u[1] = rp[p].y;
        Br.u[2] = ip[p].x ^ 0x80008000u; Br.u[3] = ip[p].y ^ 0x80008000u;
        FragU Bi; Bi.u[0] = ip[p].x; Bi.u[1] = ip[p].y; Bi.u[2] = rp[p].x; Bi.u[3] = rp[p].y;
        s2r[p] = MFMA(Afrag, Br, zero);
        s2i[p] = MFMA(Afrag, Bi, zero);
    }
    // tw256(o3*m2): o3=c, m2=4g+reg
    {
        float twc[4], tws[4];
        float sb, cb, ss, cs;
        __sincosf(K2 * (float)(c * 4 * g), &sb, &cb);
        __sincosf(K2 * (float)c, &ss, &cs);
#pragma unroll
        for (int reg = 0; reg < 4; ++reg) {
            twc[reg] = cb; tws[reg] = sb;
            const float nc = cb * cs - sb * ss;
            const float ns = cb * ss + sb * cs;
            cb = nc; sb = ns;
        }
#pragma unroll
        for (int p = 0; p < 4; ++p) {
#pragma unroll
            for (int reg = 0; reg < 4; ++reg) {
                const float yr = s2r[p][reg], yi = s2i[p][reg];
                s2r[p][reg] = yr * twc[reg] - yi * tws[reg];
                s2i[p][reg] = yr * tws[reg] + yi * twc[reg];
            }
        }
    }
    __syncthreads();   // bar2a: every wave done READING LDS1

    // LDS2 [m2][m1][o3] in place; pos = m1*16+o3, spos = pos^(m2>>2)<<4^(m2&3)<<2
#pragma unroll
    for (int reg = 0; reg < 4; ++reg) {
        const int m2 = 4 * g + reg;
#pragma unroll
        for (int p = 0; p < 4; ++p) {
            const int spos = (((4 * w + p) * 16 + c) ^ (g << 4)) ^ (reg << 2);
            const int half = m2 * 256 + spos;
            *(unsigned short*)(smem + half * 2)        = h16(s2r[p][reg]);
            *(unsigned short*)(smem + 8192 + half * 2) = h16(s2i[p][reg]);
        }
    }
    __syncthreads();   // bar2b: LDS2 ready

    // ================= stage 3: V^T[m2][n3] = sum_o3 U^T[m2][o3] M^T[o3][n3] ==
    FragU Aup[4];
#pragma unroll
    for (int p = 0; p < 4; ++p) {
        const int spos = ((((4 * w + p) * 16 + 4 * g) ^ (((c >> 2) & 3) << 4))
                          ^ ((c & 3) << 2));
        const int half = c * 256 + spos;
        const uint2 hr = *(const uint2*)(smem + half * 2);
        const uint2 hi = *(const uint2*)(smem + 8192 + half * 2);
        Aup[p].u[0] = hr.x; Aup[p].u[1] = hr.y;
        Aup[p].u[2] = hi.x; Aup[p].u[3] = hi.y;
    }
    __syncthreads();   // bar3: all LDS2 reads done before F overlays

    f32x4 vR[4], vI[4];
#pragma unroll
    for (int p = 0; p < 4; ++p) {
        vR[p] = MFMA(Aup[p], BMr, zero);
        vI[p] = MFMA(Aup[p], BMi, zero);
    }

    // F fp16: row n3=c (256 half2 words = 1KB), pair index P (2 complex).
    // P_linear = inner>>1 = (4g+reg)*8 + 2w + {0,1};
    // P_swz = P_linear ^ (row&7) ^ ((g&1)<<3)   [bit5 of P_linear == g&1]
    {
        const int key = (c & 7) ^ ((g & 1) << 3);
#pragma unroll
        for (int reg = 0; reg < 4; ++reg) {
            const int Pl = (4 * g + reg) * 8 + 2 * w;
            const int P0 = Pl ^ key, P1 = (Pl + 1) ^ key;
            uint2 v0, v1;
            v0.x = pkh(vR[0][reg], vI[0][reg]); v0.y = pkh(vR[1][reg], vI[1][reg]);
            v1.x = pkh(vR[2][reg], vI[2][reg]); v1.y = pkh(vR[3][reg], vI[3][reg]);
            *(uint2*)(smem + (size_t)(c * 256 + 2 * P0) * 4) = v0;
            *(uint2*)(smem + (size_t)(c * 256 + 2 * P1) * 4) = v1;
        }
    }
    __syncthreads();   // bar4: F ready

    // coalesced nontemporal store: 1 pair (2 complex, 16B fp32) per lane/iter
    f32x4* __restrict__ og4 = (f32x4*)out;
    const int tl = t & 127;                 // pair index within row
#pragma unroll
    for (int it = 0; it < 8; ++it) {
        const int jr = 2 * it + (t >> 7);   // row n3
        const int Ps = tl ^ (jr & 7) ^ (((tl >> 5) & 1) << 3);
        const uint2 pv = *(const uint2*)(smem + (size_t)(jr * 256 + 2 * Ps) * 4);
        H2U a, b; a.u = pv.x; b.u = pv.y;
        const f32x4 v = {(float)a.h[0], (float)a.h[1], (float)b.h[0], (float)b.h[1]};
        __builtin_nontemporal_store(v, &og4[(base >> 1) + (size_t)(jr * 128 + tl)]);
    }
}

extern "C" void kernel_launch(void* const* d_in, const int* in_sizes, int n_in,
                              void* d_out, int out_size, void* d_ws, size_t ws_size,
                              hipStream_t stream)
{
    const float* xre = (const float*)d_in[0];
    const float* xim = (const float*)d_in[1];
    const float* m16 = (const float*)d_in[5];   // (H,16,16,2) fp32
    const int H  = in_sizes[5] / 512;
    const int BH = in_sizes[0] / 4096;
    fft4096_mfma<<<dim3(BH), dim3(256), 0, stream>>>(
        xre, xim, m16, (float*)d_out, H);
}